// Round 7
// baseline (259.552 us; speedup 1.0000x reference)
//
#include <hip/hip_runtime.h>
#include <hip/hip_bf16.h>
#include <math.h>

// BilinearGate. B=8, Cin=256, HW=9216, R=32, TRI=528, Cout=256.
// v8: reduce_kernel w-stream moved to SCALAR loads. v7 was LDS-issue-bound:
// broadcast ds_read_b128 of w cost 2048 reads/wave x 12cyc -> ~46us/CU,
// matching the observed ~45us. wT reads are wave-uniform -> s_load into
// SGPRs (v_fmac_f32 takes 1 SGPR src); w rides the scalar pipe, VALU does
// pure FMA (~13.7us/SIMD wall = x-read HBM floor). No LDS, no barrier.
// Math order identical to v7 (f32 fmac, c ascending) -> same numerics.
// gemm2 (v6, proven) and convert unchanged. Fallback fused (v4) kept.
#define HW     9216
#define CIN    256
#define RCH    32
#define NTRI   528
#define COUT   256
#define NB     8
#define WFROWS 272   // 8 wv * 2 mi * 17 c fragment-rows of 512 halfs
#define UPROW  300   // halfs per upS row (288 data + 12 pad) = 600 B

typedef _Float16 f16x8 __attribute__((ext_vector_type(8)));
typedef _Float16 f16x4 __attribute__((ext_vector_type(4)));
typedef float    f32x4 __attribute__((ext_vector_type(4)));

struct TriTab { unsigned char i[544]; unsigned char j[544]; };
constexpr TriTab make_tri() {
  TriTab t{};
  int ii = 0, jj = 0;
  for (int k = 0; k < 544; ++k) {
    if (k < NTRI) {
      t.i[k] = (unsigned char)ii; t.j[k] = (unsigned char)jj;
      if (++jj == 32) { ++ii; jj = ii; }
    } else { t.i[k] = 0; t.j[k] = 0; }
  }
  return t;
}
constexpr TriTab TRI = make_tri();

// Wave TQ (0..7) builds its share of up[p][t] for one half.
// HALF 0: t in [TQ*36, TQ*36+36). HALF 1: t in [288+TQ*32, 288+TQ*32+32).
template<int TQ, int HALF>
__device__ __forceinline__ void build_up(const float (&o)[RCH], _Float16* rowp) {
  constexpr int NG  = HALF ? 8 : 9;
  constexpr int TLB = TQ * (HALF ? 32 : 36);
  constexpr int TB  = HALF ? 288 : 0;
#pragma unroll
  for (int g = 0; g < NG; ++g) {
    f16x4 v;
#pragma unroll
    for (int s = 0; s < 4; ++s) {
      const int tl = TLB + g * 4 + s;
      const int t  = TB + tl;
      float f = (t < NTRI) ? o[TRI.i[t]] * o[TRI.j[t]] : 0.0f;
      v[s] = (_Float16)f;
    }
    *(f16x4*)&rowp[TLB + g * 4] = v;
  }
}

template<int HALF>
__device__ __forceinline__ void build_dispatch(int wv, const float (&o)[RCH],
                                               _Float16* rowp) {
  switch (wv) {
    case 0: build_up<0, HALF>(o, rowp); break;
    case 1: build_up<1, HALF>(o, rowp); break;
    case 2: build_up<2, HALF>(o, rowp); break;
    case 3: build_up<3, HALF>(o, rowp); break;
    case 4: build_up<4, HALF>(o, rowp); break;
    case 5: build_up<5, HALF>(o, rowp); break;
    case 6: build_up<6, HALF>(o, rowp); break;
    default: build_up<7, HALF>(o, rowp); break;
  }
}

// w16 fragment layout: element (((wv*2+mi)*17 + c)*64 + lane)*8 + s holds
// w_recover[o][t] with o = wv*32+mi*16+(lane&15), t = c*32+(lane>>4)*8+s.
// wT layout: wT[c*32 + r] = w_reduce[r*256 + c] (f32, 32 KB).
__global__ __launch_bounds__(256) void convert_kernel(
    const float* __restrict__ w_reduce, const float* __restrict__ w_recover,
    _Float16* __restrict__ w16, _Float16* __restrict__ wr16h,
    _Float16* __restrict__ wr16l, float* __restrict__ wT) {
  const int bx = blockIdx.x;
  const int tid = threadIdx.x;
  if (bx < WFROWS) {
    const int wv  = bx / 34;
    const int rem = bx - wv * 34;
    const int mi  = rem / 17;
    const int c   = rem - mi * 17;
    const int lane = tid >> 2;           // 0..63
    const int s0   = (tid & 3) * 2;      // 0,2,4,6
    const int o = wv * 32 + mi * 16 + (lane & 15);
    const int t = c * 32 + (lane >> 4) * 8 + s0;
    float f0 = (t     < NTRI) ? w_recover[(size_t)o * NTRI + t]     : 0.0f;
    float f1 = (t + 1 < NTRI) ? w_recover[(size_t)o * NTRI + t + 1] : 0.0f;
    _Float16* p = &w16[((size_t)bx * 64 + lane) * 8 + s0];
    p[0] = (_Float16)f0;
    p[1] = (_Float16)f1;
  } else if (bx < WFROWS + 16) {
    int e = (bx - WFROWS) * 512 + tid;
#pragma unroll
    for (int k = 0; k < 2; ++k, e += 256) {
      float f = w_reduce[e];
      _Float16 h = (_Float16)f;
      wr16h[e] = h;
      wr16l[e] = (_Float16)(f - (float)h);
    }
  } else {
    // wT fill: 8192 f32, one block, 32 per thread
#pragma unroll
    for (int k = 0; k < 32; ++k) {
      const int e = k * 256 + tid;       // e = c*32 + r
      const int c = e >> 5;
      const int r = e & 31;
      wT[e] = w_reduce[r * CIN + c];
    }
  }
}

// ---------------- GEMM1 scalar-w streaming kernel: out[b][r][px] ------------
// 576 blocks (8 b * 72 tiles of 128 px), 128 threads. Thread owns one px.
// w via wave-uniform global reads -> s_load into SGPRs (scalar pipe);
// x via coalesced 256B rows, 16-channel depth-1 prefetch; 32 v_fmac_f32/c.
__global__ __launch_bounds__(128) void reduce_kernel(
    const float* __restrict__ x, const float* __restrict__ wT,
    float* __restrict__ out) {
  const int tid = threadIdx.x;
  const int bx  = blockIdx.x;            // 576 = 8 b * 72
  const int b   = bx / 72;
  const int p0  = (bx - b * 72) * 128;

  float acc[RCH];
#pragma unroll
  for (int r = 0; r < RCH; ++r) acc[r] = 0.0f;

  const float* xb = x + (size_t)b * CIN * HW + p0 + tid;

  // 16 groups of 16 channels, depth-1 prefetch, fully unrolled (static idx).
  float xv[2][16];
#pragma unroll
  for (int j = 0; j < 16; ++j)
    xv[0][j] = xb[(size_t)j * HW];

#pragma unroll
  for (int g = 0; g < 16; ++g) {
    const int cur = g & 1, nxt = cur ^ 1;
    if (g < 15) {
#pragma unroll
      for (int j = 0; j < 16; ++j)
        xv[nxt][j] = xb[(size_t)((g + 1) * 16 + j) * HW];
      __builtin_amdgcn_sched_group_barrier(0x020, 16, 0);  // keep prefetch batched
    }
#pragma unroll
    for (int j = 0; j < 16; ++j) {
      const float xc = xv[cur][j];
      // wave-uniform address -> scalar loads (s_load_dwordx4)
      const float* wrow = &wT[(g * 16 + j) * RCH];
#pragma unroll
      for (int r8 = 0; r8 < 8; ++r8) {
        f32x4 w4 = *(const f32x4*)&wrow[r8 * 4];
        acc[r8 * 4 + 0] += w4[0] * xc;
        acc[r8 * 4 + 1] += w4[1] * xc;
        acc[r8 * 4 + 2] += w4[2] * xc;
        acc[r8 * 4 + 3] += w4[3] * xc;
      }
    }
  }

  // out[(b*32 + r)*HW + px], px = p0+tid: 32 coalesced dword stores.
#pragma unroll
  for (int r = 0; r < RCH; ++r)
    out[((size_t)(b * RCH + r)) * HW + p0 + tid] = acc[r];
}

// ---------------- GEMM2 kernel: up-build + 17 chunks (v6, proven) -----------
__global__ __launch_bounds__(512, 4) void gemm2_kernel(
    const float* __restrict__ outp, const _Float16* __restrict__ w16,
    float* __restrict__ y) {
  __shared__ __align__(16) _Float16 upS[64 * UPROW];   // 38.4 KB (only LDS)

  const int tid  = threadIdx.x;
  const int bx   = blockIdx.x;          // 1152 = 8 b * 144 px-tiles
  const int b    = bx / 144;
  const int p0   = (bx - b * 144) * 64;
  const int wv   = tid >> 6;
  const int lane = tid & 63;
  const int ml   = lane & 15;
  const int q    = lane >> 4;

  // o-vector: lane owns px = p0+lane; 32 coalesced dword loads (L2/L3-hot).
  const float* ob = outp + (size_t)b * RCH * HW + p0 + lane;
  float o0[RCH];
#pragma unroll
  for (int r = 0; r < RCH; ++r) o0[r] = ob[(size_t)r * HW];

  // Fragment bases into pre-swizzled w16 (chunk c at +c*512 halfs).
  const _Float16* wf0 = w16 + ((size_t)(wv * 2 + 0) * 17 * 64 + lane) * 8;
  const _Float16* wf1 = w16 + ((size_t)(wv * 2 + 1) * 17 * 64 + lane) * 8;

  // A-stream depth-2 prologue: chunks 0,1 in flight during build0.
  f16x8 abuf[3][2];
  abuf[0][0] = *(const f16x8*)&wf0[0];
  abuf[0][1] = *(const f16x8*)&wf1[0];
  abuf[1][0] = *(const f16x8*)&wf0[512];
  abuf[1][1] = *(const f16x8*)&wf1[512];

  f32x4 acc[2][4];
#pragma unroll
  for (int mi = 0; mi < 2; ++mi)
#pragma unroll
    for (int ni = 0; ni < 4; ++ni)
#pragma unroll
      for (int r2 = 0; r2 < 4; ++r2) acc[mi][ni][r2] = 0.0f;

  _Float16* rowp = &upS[lane * UPROW];

  // ---------------- HALF 0: build t[0,288) then chunks c=0..8 -------------
  build_dispatch<0>(wv, o0, rowp);
  __syncthreads();   // barrier 1: upS half0 ready

  f16x8 bbuf[2][4];
#pragma unroll
  for (int ni = 0; ni < 4; ++ni)
    bbuf[0][ni] = *(const f16x8*)&upS[(ni * 16 + ml) * UPROW + q * 8];

#pragma unroll
  for (int c = 0; c < 9; ++c) {
    const int cur = c % 3;
    const int pf  = (c + 2) % 3;     // chunks c+2 <= 10 < 17: always valid
    abuf[pf][0] = *(const f16x8*)&wf0[(size_t)(c + 2) * 512];
    abuf[pf][1] = *(const f16x8*)&wf1[(size_t)(c + 2) * 512];
    const int cb = c & 1, nb = cb ^ 1;
    if (c < 8) {
      const int t0n = (c + 1) * 32;
#pragma unroll
      for (int ni = 0; ni < 4; ++ni)
        bbuf[nb][ni] = *(const f16x8*)&upS[(ni * 16 + ml) * UPROW + t0n + q * 8];
    }
#pragma unroll
    for (int ni = 0; ni < 4; ++ni) {
      acc[0][ni] = __builtin_amdgcn_mfma_f32_16x16x32_f16(abuf[cur][0], bbuf[cb][ni], acc[0][ni], 0, 0, 0);
      acc[1][ni] = __builtin_amdgcn_mfma_f32_16x16x32_f16(abuf[cur][1], bbuf[cb][ni], acc[1][ni], 0, 0, 0);
    }
    __builtin_amdgcn_sched_group_barrier(0x020, 2, 0);     // A prefetch
    if (c < 8)
      __builtin_amdgcn_sched_group_barrier(0x100, 4, 0);   // B ds_reads
    __builtin_amdgcn_sched_group_barrier(0x008, 8, 0);     // MFMAs
  }

  // Reload o (L2-hot, coalesced); in flight across the barrier.
  float o1[RCH];
#pragma unroll
  for (int r = 0; r < RCH; ++r) o1[r] = ob[(size_t)r * HW];

  __syncthreads();   // barrier 2: half0 reads done (WAR before overwrite)

  // ---------------- HALF 1: build t[288,544) then chunks g=9..16 ----------
  build_dispatch<1>(wv, o1, rowp);
  __syncthreads();   // barrier 3: upS half1 ready
  // abuf slots hold chunk 9 (slot 0) and 10 (slot 1).

#pragma unroll
  for (int ni = 0; ni < 4; ++ni)
    bbuf[0][ni] = *(const f16x8*)&upS[(ni * 16 + ml) * UPROW + q * 8];

#pragma unroll
  for (int cc = 0; cc < 8; ++cc) {
    const int cur = cc % 3;          // global chunk g=9+cc, (9+cc)%3 == cc%3
    if (cc < 6) {
      const int pf = (2 + cc) % 3;   // chunk 11+cc, valid while 11+cc <= 16
      abuf[pf][0] = *(const f16x8*)&wf0[(size_t)(11 + cc) * 512];
      abuf[pf][1] = *(const f16x8*)&wf1[(size_t)(11 + cc) * 512];
    }
    const int cb = cc & 1, nb = cb ^ 1;
    if (cc < 7) {
      const int t0n = (cc + 1) * 32;
#pragma unroll
      for (int ni = 0; ni < 4; ++ni)
        bbuf[nb][ni] = *(const f16x8*)&upS[(ni * 16 + ml) * UPROW + t0n + q * 8];
    }
#pragma unroll
    for (int ni = 0; ni < 4; ++ni) {
      acc[0][ni] = __builtin_amdgcn_mfma_f32_16x16x32_f16(abuf[cur][0], bbuf[cb][ni], acc[0][ni], 0, 0, 0);
      acc[1][ni] = __builtin_amdgcn_mfma_f32_16x16x32_f16(abuf[cur][1], bbuf[cb][ni], acc[1][ni], 0, 0, 0);
    }
    if (cc < 6)
      __builtin_amdgcn_sched_group_barrier(0x020, 2, 0);   // A prefetch
    if (cc < 7)
      __builtin_amdgcn_sched_group_barrier(0x100, 4, 0);   // B ds_reads
    __builtin_amdgcn_sched_group_barrier(0x008, 8, 0);     // MFMAs
  }

  // ---------------- Epilogue: signed sqrt, dword stores -------------------
#pragma unroll
  for (int mi = 0; mi < 2; ++mi) {
#pragma unroll
    for (int reg = 0; reg < 4; ++reg) {
      const int o = wv * 32 + mi * 16 + q * 4 + reg;
      float* yrow = y + ((size_t)(b * COUT + o)) * HW + p0 + ml;
#pragma unroll
      for (int ni = 0; ni < 4; ++ni) {
        float v = acc[mi][ni][reg];
        float s = sqrtf(fabsf(v) + 1e-6f);
        yrow[ni * 16] = v > 0.0f ? s : (v < 0.0f ? -s : 0.0f);
      }
    }
  }
}

// ---------------- Fallback fused kernel (v4, proven) if ws too small -------
__global__ __launch_bounds__(512, 4) void fused_kernel(
    const float* __restrict__ x, const _Float16* __restrict__ w16,
    const _Float16* __restrict__ wr16h, const _Float16* __restrict__ wr16l,
    float* __restrict__ y) {
  __shared__ float outS[RCH * 68];
  __shared__ __align__(16) _Float16 upS[64 * UPROW];

  const int tid  = threadIdx.x;
  const int bx   = blockIdx.x;
  const int b    = bx / 144;
  const int p0   = (bx - b * 144) * 64;
  const int wv   = tid >> 6;
  const int lane = tid & 63;
  const int ml   = lane & 15;
  const int q    = lane >> 4;
  const int mt   = wv >> 2;
  const int nt   = wv & 3;

  {
    f32x4 g1acc;
#pragma unroll
    for (int r2 = 0; r2 < 4; ++r2) g1acc[r2] = 0.0f;

    const int abase = (mt * 16 + ml) * CIN + q * 8;
    f16x8 pa[3][2];
    pa[0][0] = *(const f16x8*)&wr16h[abase + 0 * 32];
    pa[0][1] = *(const f16x8*)&wr16l[abase + 0 * 32];
    pa[1][0] = *(const f16x8*)&wr16h[abase + 1 * 32];
    pa[1][1] = *(const f16x8*)&wr16l[abase + 1 * 32];

    const float* xb = x + (size_t)b * CIN * HW + p0 + nt * 16 + ml;
    float xv[64];
#pragma unroll
    for (int ch = 0; ch < 8; ++ch)
#pragma unroll
      for (int s = 0; s < 8; ++s)
        xv[ch * 8 + s] = xb[(size_t)(ch * 32 + q * 8 + s) * HW];
    __builtin_amdgcn_sched_barrier(0);

#pragma unroll
    for (int ch = 0; ch < 8; ++ch) {
      const int cur = ch % 3;
      if (ch + 2 < 8) {
        const int pf = (ch + 2) % 3;
        pa[pf][0] = *(const f16x8*)&wr16h[abase + (ch + 2) * 32];
        pa[pf][1] = *(const f16x8*)&wr16l[abase + (ch + 2) * 32];
      }
      f16x8 bh, bl;
#pragma unroll
      for (int s = 0; s < 8; ++s) {
        float f = xv[ch * 8 + s];
        _Float16 h = (_Float16)f;
        bh[s] = h;
        bl[s] = (_Float16)(f - (float)h);
      }
      g1acc = __builtin_amdgcn_mfma_f32_16x16x32_f16(pa[cur][0], bh, g1acc, 0, 0, 0);
      g1acc = __builtin_amdgcn_mfma_f32_16x16x32_f16(pa[cur][1], bh, g1acc, 0, 0, 0);
      g1acc = __builtin_amdgcn_mfma_f32_16x16x32_f16(pa[cur][0], bl, g1acc, 0, 0, 0);
    }
#pragma unroll
    for (int reg = 0; reg < 4; ++reg)
      outS[(mt * 16 + q * 4 + reg) * 68 + nt * 16 + ml] = g1acc[reg];
  }

  const _Float16* wf0 = w16 + ((size_t)(wv * 2 + 0) * 17 * 64 + lane) * 8;
  const _Float16* wf1 = w16 + ((size_t)(wv * 2 + 1) * 17 * 64 + lane) * 8;

  f16x8 abuf[3][2];
  abuf[0][0] = *(const f16x8*)&wf0[0];
  abuf[0][1] = *(const f16x8*)&wf1[0];
  abuf[1][0] = *(const f16x8*)&wf0[512];
  abuf[1][1] = *(const f16x8*)&wf1[512];

  __syncthreads();

  f32x4 acc[2][4];
#pragma unroll
  for (int mi = 0; mi < 2; ++mi)
#pragma unroll
    for (int ni = 0; ni < 4; ++ni)
#pragma unroll
      for (int r2 = 0; r2 < 4; ++r2) acc[mi][ni][r2] = 0.0f;

  _Float16* rowp = &upS[lane * UPROW];

  {
    float o[RCH];
#pragma unroll
    for (int r = 0; r < RCH; ++r) o[r] = outS[r * 68 + lane];
    build_dispatch<0>(wv, o, rowp);
  }
  __syncthreads();

  f16x8 bbuf[2][4];
#pragma unroll
  for (int ni = 0; ni < 4; ++ni)
    bbuf[0][ni] = *(const f16x8*)&upS[(ni * 16 + ml) * UPROW + q * 8];

#pragma unroll
  for (int c = 0; c < 9; ++c) {
    const int cur = c % 3;
    const int pf  = (c + 2) % 3;
    abuf[pf][0] = *(const f16x8*)&wf0[(size_t)(c + 2) * 512];
    abuf[pf][1] = *(const f16x8*)&wf1[(size_t)(c + 2) * 512];
    const int cb = c & 1, nb = cb ^ 1;
    if (c < 8) {
      const int t0n = (c + 1) * 32;
#pragma unroll
      for (int ni = 0; ni < 4; ++ni)
        bbuf[nb][ni] = *(const f16x8*)&upS[(ni * 16 + ml) * UPROW + t0n + q * 8];
    }
#pragma unroll
    for (int ni = 0; ni < 4; ++ni) {
      acc[0][ni] = __builtin_amdgcn_mfma_f32_16x16x32_f16(abuf[cur][0], bbuf[cb][ni], acc[0][ni], 0, 0, 0);
      acc[1][ni] = __builtin_amdgcn_mfma_f32_16x16x32_f16(abuf[cur][1], bbuf[cb][ni], acc[1][ni], 0, 0, 0);
    }
  }
  __syncthreads();

  {
    float o[RCH];
#pragma unroll
    for (int r = 0; r < RCH; ++r) o[r] = outS[r * 68 + lane];
    build_dispatch<1>(wv, o, rowp);
  }
  __syncthreads();

#pragma unroll
  for (int ni = 0; ni < 4; ++ni)
    bbuf[0][ni] = *(const f16x8*)&upS[(ni * 16 + ml) * UPROW + q * 8];

#pragma unroll
  for (int cc = 0; cc < 8; ++cc) {
    const int cur = cc % 3;
    if (cc < 6) {
      const int pf = (2 + cc) % 3;
      abuf[pf][0] = *(const f16x8*)&wf0[(size_t)(11 + cc) * 512];
      abuf[pf][1] = *(const f16x8*)&wf1[(size_t)(11 + cc) * 512];
    }
    const int cb = cc & 1, nb = cb ^ 1;
    if (cc < 7) {
      const int t0n = (cc + 1) * 32;
#pragma unroll
      for (int ni = 0; ni < 4; ++ni)
        bbuf[nb][ni] = *(const f16x8*)&upS[(ni * 16 + ml) * UPROW + t0n + q * 8];
    }
#pragma unroll
    for (int ni = 0; ni < 4; ++ni) {
      acc[0][ni] = __builtin_amdgcn_mfma_f32_16x16x32_f16(abuf[cur][0], bbuf[cb][ni], acc[0][ni], 0, 0, 0);
      acc[1][ni] = __builtin_amdgcn_mfma_f32_16x16x32_f16(abuf[cur][1], bbuf[cb][ni], acc[1][ni], 0, 0, 0);
    }
  }

#pragma unroll
  for (int mi = 0; mi < 2; ++mi) {
#pragma unroll
    for (int reg = 0; reg < 4; ++reg) {
      const int o = wv * 32 + mi * 16 + q * 4 + reg;
      float* yrow = y + ((size_t)(b * COUT + o)) * HW + p0 + ml;
#pragma unroll
      for (int ni = 0; ni < 4; ++ni) {
        float v = acc[mi][ni][reg];
        float s = sqrtf(fabsf(v) + 1e-6f);
        yrow[ni * 16] = v > 0.0f ? s : (v < 0.0f ? -s : 0.0f);
      }
    }
  }
}

extern "C" void kernel_launch(void* const* d_in, const int* in_sizes, int n_in,
                              void* d_out, int out_size, void* d_ws, size_t ws_size,
                              hipStream_t stream) {
  const float* x         = (const float*)d_in[0];
  const float* w_reduce  = (const float*)d_in[1];
  const float* w_recover = (const float*)d_in[2];
  float* y = (float*)d_out;

  _Float16* w16   = (_Float16*)d_ws;                            // 278528 B
  _Float16* wr16h = (_Float16*)((char*)d_ws + 278528);          // 16384 B
  _Float16* wr16l = (_Float16*)((char*)d_ws + 278528 + 16384);  // 16384 B
  float*    wT    = (float*)((char*)d_ws + 311296);             // 32768 B
  float*    outp  = (float*)((char*)d_ws + 344064);             // 9437184 B
  const size_t NEED = 344064 + (size_t)NB * RCH * HW * 4;

  convert_kernel<<<WFROWS + 17, 256, 0, stream>>>(w_reduce, w_recover, w16,
                                                  wr16h, wr16l, wT);
  if (ws_size >= NEED) {
    reduce_kernel<<<NB * (HW / 128), 128, 0, stream>>>(x, wT, outp);
    gemm2_kernel<<<NB * (HW / 64), 512, 0, stream>>>(outp, w16, y);
  } else {
    fused_kernel<<<NB * (HW / 64), 512, 0, stream>>>(x, w16, wr16h, wr16l, y);
  }
}

// Round 8
// 168.157 us; speedup vs baseline: 1.5435x; 1.5435x over previous
//
#include <hip/hip_runtime.h>
#include <hip/hip_bf16.h>
#include <math.h>

// BilinearGate. B=8, Cin=256, HW=9216, R=32, TRI=528, Cout=256.
// v9: reduce = MFMA with x staged via LDS. Session ledger: v6-MFMA (strided
// x) 45us; v7-VALU (broadcast ds_read issue-bound: 2048 reads/wave) 45us;
// v8-scalar (exposed L2 latency) 123us. This design dodges all three:
// - x: HBM->LDS coalesced (b128 global, b64 ds_write), dbuf per 32-ch chunk
// - w: A-frags b128 from L2 (v0-proven mapping), depth-1 prefetch
// - B-frags: per-lane b32 LDS reads (128/wave, 16x fewer than v7)
// - [c][130] padding: 2-way read conflicts = free (m136)
// All MFMA/store mappings are v0/v6-proven. gemm2/convert unchanged.
#define HW     9216
#define CIN    256
#define RCH    32
#define NTRI   528
#define COUT   256
#define NB     8
#define WFROWS 272   // 8 wv * 2 mi * 17 c fragment-rows of 512 halfs
#define UPROW  300   // halfs per upS row (288 data + 12 pad) = 600 B
#define PXW    130   // xS row stride in dwords (128 + 2 pad)

typedef _Float16 f16x8 __attribute__((ext_vector_type(8)));
typedef _Float16 f16x4 __attribute__((ext_vector_type(4)));
typedef float    f32x4 __attribute__((ext_vector_type(4)));
typedef float    f32x2 __attribute__((ext_vector_type(2)));

struct TriTab { unsigned char i[544]; unsigned char j[544]; };
constexpr TriTab make_tri() {
  TriTab t{};
  int ii = 0, jj = 0;
  for (int k = 0; k < 544; ++k) {
    if (k < NTRI) {
      t.i[k] = (unsigned char)ii; t.j[k] = (unsigned char)jj;
      if (++jj == 32) { ++ii; jj = ii; }
    } else { t.i[k] = 0; t.j[k] = 0; }
  }
  return t;
}
constexpr TriTab TRI = make_tri();

// Wave TQ (0..7) builds its share of up[p][t] for one half.
// HALF 0: t in [TQ*36, TQ*36+36). HALF 1: t in [288+TQ*32, 288+TQ*32+32).
template<int TQ, int HALF>
__device__ __forceinline__ void build_up(const float (&o)[RCH], _Float16* rowp) {
  constexpr int NG  = HALF ? 8 : 9;
  constexpr int TLB = TQ * (HALF ? 32 : 36);
  constexpr int TB  = HALF ? 288 : 0;
#pragma unroll
  for (int g = 0; g < NG; ++g) {
    f16x4 v;
#pragma unroll
    for (int s = 0; s < 4; ++s) {
      const int tl = TLB + g * 4 + s;
      const int t  = TB + tl;
      float f = (t < NTRI) ? o[TRI.i[t]] * o[TRI.j[t]] : 0.0f;
      v[s] = (_Float16)f;
    }
    *(f16x4*)&rowp[TLB + g * 4] = v;
  }
}

template<int HALF>
__device__ __forceinline__ void build_dispatch(int wv, const float (&o)[RCH],
                                               _Float16* rowp) {
  switch (wv) {
    case 0: build_up<0, HALF>(o, rowp); break;
    case 1: build_up<1, HALF>(o, rowp); break;
    case 2: build_up<2, HALF>(o, rowp); break;
    case 3: build_up<3, HALF>(o, rowp); break;
    case 4: build_up<4, HALF>(o, rowp); break;
    case 5: build_up<5, HALF>(o, rowp); break;
    case 6: build_up<6, HALF>(o, rowp); break;
    default: build_up<7, HALF>(o, rowp); break;
  }
}

// w16 fragment layout: element (((wv*2+mi)*17 + c)*64 + lane)*8 + s holds
// w_recover[o][t] with o = wv*32+mi*16+(lane&15), t = c*32+(lane>>4)*8+s.
// wT layout: wT[c*32 + r] = w_reduce[r*256 + c] (f32, 32 KB; kept for ABI).
__global__ __launch_bounds__(256) void convert_kernel(
    const float* __restrict__ w_reduce, const float* __restrict__ w_recover,
    _Float16* __restrict__ w16, _Float16* __restrict__ wr16h,
    _Float16* __restrict__ wr16l, float* __restrict__ wT) {
  const int bx = blockIdx.x;
  const int tid = threadIdx.x;
  if (bx < WFROWS) {
    const int wv  = bx / 34;
    const int rem = bx - wv * 34;
    const int mi  = rem / 17;
    const int c   = rem - mi * 17;
    const int lane = tid >> 2;           // 0..63
    const int s0   = (tid & 3) * 2;      // 0,2,4,6
    const int o = wv * 32 + mi * 16 + (lane & 15);
    const int t = c * 32 + (lane >> 4) * 8 + s0;
    float f0 = (t     < NTRI) ? w_recover[(size_t)o * NTRI + t]     : 0.0f;
    float f1 = (t + 1 < NTRI) ? w_recover[(size_t)o * NTRI + t + 1] : 0.0f;
    _Float16* p = &w16[((size_t)bx * 64 + lane) * 8 + s0];
    p[0] = (_Float16)f0;
    p[1] = (_Float16)f1;
  } else if (bx < WFROWS + 16) {
    int e = (bx - WFROWS) * 512 + tid;
#pragma unroll
    for (int k = 0; k < 2; ++k, e += 256) {
      float f = w_reduce[e];
      _Float16 h = (_Float16)f;
      wr16h[e] = h;
      wr16l[e] = (_Float16)(f - (float)h);
    }
  } else {
    // wT fill: 8192 f32, one block, 32 per thread
#pragma unroll
    for (int k = 0; k < 32; ++k) {
      const int e = k * 256 + tid;       // e = c*32 + r
      const int c = e >> 5;
      const int r = e & 31;
      wT[e] = w_reduce[r * CIN + c];
    }
  }
}

// ---------------- GEMM1 MFMA kernel, LDS-staged x: out[b][r][px] ------------
// 576 blocks (8 b * 72 tiles of 128 px), 256 threads (4 waves).
// Wave wv owns px columns [wv*32, +32) (2 n-tiles), all 32 r (2 m-tiles).
// Per 32-ch chunk: x staged HBM->LDS (coalesced), A-frags b128 from L2,
// B-frags per-lane b32 from LDS (v0-proven fragment mappings throughout).
__global__ __launch_bounds__(256) void reduce_kernel(
    const float* __restrict__ x, const _Float16* __restrict__ wr16h,
    const _Float16* __restrict__ wr16l, float* __restrict__ out) {
  __shared__ __align__(16) float xS[2][RCH][PXW];   // 33.3 KB

  const int tid  = threadIdx.x;
  const int bx   = blockIdx.x;          // 576 = 8 b * 72 px-tiles
  const int b    = bx / 72;
  const int p0   = (bx - b * 72) * 128;
  const int wv   = tid >> 6;
  const int lane = tid & 63;
  const int ml   = lane & 15;
  const int q    = lane >> 4;
  const int ci   = tid >> 5;            // 0..7 (staging c-row)
  const int pxi  = (tid & 31) * 4;      // 0..124 (staging px base)

  const float* xg = x + (size_t)b * CIN * HW + p0 + pxi;
  const int arow0 = (0 * 16 + ml) * CIN + q * 8;
  const int arow1 = (1 * 16 + ml) * CIN + q * 8;

  f32x4 acc[2][2];
#pragma unroll
  for (int mt = 0; mt < 2; ++mt)
#pragma unroll
    for (int nt = 0; nt < 2; ++nt)
#pragma unroll
      for (int r2 = 0; r2 < 4; ++r2) acc[mt][nt][r2] = 0.0f;

  // ---- prologue: stage chunk 0 into buf 0; A-frags for chunk 0 ----
  f32x4 gx[4];
#pragma unroll
  for (int k = 0; k < 4; ++k)
    gx[k] = *(const f32x4*)&xg[(size_t)(ci + 8 * k) * HW];

  f16x8 af[2][2][2];                    // [parity][mt][h/l]
  af[0][0][0] = *(const f16x8*)&wr16h[arow0];
  af[0][0][1] = *(const f16x8*)&wr16l[arow0];
  af[0][1][0] = *(const f16x8*)&wr16h[arow1];
  af[0][1][1] = *(const f16x8*)&wr16l[arow1];

#pragma unroll
  for (int k = 0; k < 4; ++k) {
    *(f32x2*)&xS[0][ci + 8 * k][pxi]     = f32x2{gx[k][0], gx[k][1]};
    *(f32x2*)&xS[0][ci + 8 * k][pxi + 2] = f32x2{gx[k][2], gx[k][3]};
  }
  __syncthreads();

  // ---- main loop: 8 chunks of K=32, depth-1 dbuf ----
#pragma unroll
  for (int ch = 0; ch < 8; ++ch) {
    const int cur = ch & 1, nxt = cur ^ 1;
    if (ch < 7) {
      const int c0n = (ch + 1) * 32;
#pragma unroll
      for (int k = 0; k < 4; ++k)
        gx[k] = *(const f32x4*)&xg[(size_t)(c0n + ci + 8 * k) * HW];
      af[nxt][0][0] = *(const f16x8*)&wr16h[arow0 + c0n];
      af[nxt][0][1] = *(const f16x8*)&wr16l[arow0 + c0n];
      af[nxt][1][0] = *(const f16x8*)&wr16h[arow1 + c0n];
      af[nxt][1][1] = *(const f16x8*)&wr16l[arow1 + c0n];
    }
#pragma unroll
    for (int nt = 0; nt < 2; ++nt) {
      const int pxc = wv * 32 + nt * 16 + ml;
      float bf[8];
#pragma unroll
      for (int s = 0; s < 8; ++s) bf[s] = xS[cur][q * 8 + s][pxc];
      f16x8 bh, bl;
#pragma unroll
      for (int s = 0; s < 8; ++s) {
        _Float16 h = (_Float16)bf[s];
        bh[s] = h;
        bl[s] = (_Float16)(bf[s] - (float)h);
      }
      acc[0][nt] = __builtin_amdgcn_mfma_f32_16x16x32_f16(af[cur][0][0], bh, acc[0][nt], 0, 0, 0);
      acc[0][nt] = __builtin_amdgcn_mfma_f32_16x16x32_f16(af[cur][0][1], bh, acc[0][nt], 0, 0, 0);
      acc[0][nt] = __builtin_amdgcn_mfma_f32_16x16x32_f16(af[cur][0][0], bl, acc[0][nt], 0, 0, 0);
      acc[1][nt] = __builtin_amdgcn_mfma_f32_16x16x32_f16(af[cur][1][0], bh, acc[1][nt], 0, 0, 0);
      acc[1][nt] = __builtin_amdgcn_mfma_f32_16x16x32_f16(af[cur][1][1], bh, acc[1][nt], 0, 0, 0);
      acc[1][nt] = __builtin_amdgcn_mfma_f32_16x16x32_f16(af[cur][1][0], bl, acc[1][nt], 0, 0, 0);
    }
    if (ch < 7) {
#pragma unroll
      for (int k = 0; k < 4; ++k) {
        *(f32x2*)&xS[nxt][ci + 8 * k][pxi]     = f32x2{gx[k][0], gx[k][1]};
        *(f32x2*)&xS[nxt][ci + 8 * k][pxi + 2] = f32x2{gx[k][2], gx[k][3]};
      }
      // pin: 8 VMEM prefetch first, then LDS reads/VALU/MFMA, writes last
      __builtin_amdgcn_sched_group_barrier(0x020, 8, 0);   // global prefetch
      __builtin_amdgcn_sched_group_barrier(0x100, 16, 0);  // B ds_reads
      __builtin_amdgcn_sched_group_barrier(0x002, 48, 0);  // cvt VALU
      __builtin_amdgcn_sched_group_barrier(0x008, 12, 0);  // MFMAs
      __builtin_amdgcn_sched_group_barrier(0x200, 8, 0);   // ds_writes
      __syncthreads();
    }
  }

  // ---- epilogue: out[(b*32 + r)*HW + px] (v6-proven pair) ----
#pragma unroll
  for (int mt = 0; mt < 2; ++mt)
#pragma unroll
    for (int nt = 0; nt < 2; ++nt)
#pragma unroll
      for (int reg = 0; reg < 4; ++reg)
        out[((size_t)(b * RCH + mt * 16 + q * 4 + reg)) * HW + p0 + wv * 32 +
            nt * 16 + ml] = acc[mt][nt][reg];
}

// ---------------- GEMM2 kernel: up-build + 17 chunks (v6, proven) -----------
__global__ __launch_bounds__(512, 4) void gemm2_kernel(
    const float* __restrict__ outp, const _Float16* __restrict__ w16,
    float* __restrict__ y) {
  __shared__ __align__(16) _Float16 upS[64 * UPROW];   // 38.4 KB (only LDS)

  const int tid  = threadIdx.x;
  const int bx   = blockIdx.x;          // 1152 = 8 b * 144 px-tiles
  const int b    = bx / 144;
  const int p0   = (bx - b * 144) * 64;
  const int wv   = tid >> 6;
  const int lane = tid & 63;
  const int ml   = lane & 15;
  const int q    = lane >> 4;

  // o-vector: lane owns px = p0+lane; 32 coalesced dword loads (L2/L3-hot).
  const float* ob = outp + (size_t)b * RCH * HW + p0 + lane;
  float o0[RCH];
#pragma unroll
  for (int r = 0; r < RCH; ++r) o0[r] = ob[(size_t)r * HW];

  // Fragment bases into pre-swizzled w16 (chunk c at +c*512 halfs).
  const _Float16* wf0 = w16 + ((size_t)(wv * 2 + 0) * 17 * 64 + lane) * 8;
  const _Float16* wf1 = w16 + ((size_t)(wv * 2 + 1) * 17 * 64 + lane) * 8;

  // A-stream depth-2 prologue: chunks 0,1 in flight during build0.
  f16x8 abuf[3][2];
  abuf[0][0] = *(const f16x8*)&wf0[0];
  abuf[0][1] = *(const f16x8*)&wf1[0];
  abuf[1][0] = *(const f16x8*)&wf0[512];
  abuf[1][1] = *(const f16x8*)&wf1[512];

  f32x4 acc[2][4];
#pragma unroll
  for (int mi = 0; mi < 2; ++mi)
#pragma unroll
    for (int ni = 0; ni < 4; ++ni)
#pragma unroll
      for (int r2 = 0; r2 < 4; ++r2) acc[mi][ni][r2] = 0.0f;

  _Float16* rowp = &upS[lane * UPROW];

  // ---------------- HALF 0: build t[0,288) then chunks c=0..8 -------------
  build_dispatch<0>(wv, o0, rowp);
  __syncthreads();   // barrier 1: upS half0 ready

  f16x8 bbuf[2][4];
#pragma unroll
  for (int ni = 0; ni < 4; ++ni)
    bbuf[0][ni] = *(const f16x8*)&upS[(ni * 16 + ml) * UPROW + q * 8];

#pragma unroll
  for (int c = 0; c < 9; ++c) {
    const int cur = c % 3;
    const int pf  = (c + 2) % 3;     // chunks c+2 <= 10 < 17: always valid
    abuf[pf][0] = *(const f16x8*)&wf0[(size_t)(c + 2) * 512];
    abuf[pf][1] = *(const f16x8*)&wf1[(size_t)(c + 2) * 512];
    const int cb = c & 1, nb = cb ^ 1;
    if (c < 8) {
      const int t0n = (c + 1) * 32;
#pragma unroll
      for (int ni = 0; ni < 4; ++ni)
        bbuf[nb][ni] = *(const f16x8*)&upS[(ni * 16 + ml) * UPROW + t0n + q * 8];
    }
#pragma unroll
    for (int ni = 0; ni < 4; ++ni) {
      acc[0][ni] = __builtin_amdgcn_mfma_f32_16x16x32_f16(abuf[cur][0], bbuf[cb][ni], acc[0][ni], 0, 0, 0);
      acc[1][ni] = __builtin_amdgcn_mfma_f32_16x16x32_f16(abuf[cur][1], bbuf[cb][ni], acc[1][ni], 0, 0, 0);
    }
    __builtin_amdgcn_sched_group_barrier(0x020, 2, 0);     // A prefetch
    if (c < 8)
      __builtin_amdgcn_sched_group_barrier(0x100, 4, 0);   // B ds_reads
    __builtin_amdgcn_sched_group_barrier(0x008, 8, 0);     // MFMAs
  }

  // Reload o (L2-hot, coalesced); in flight across the barrier.
  float o1[RCH];
#pragma unroll
  for (int r = 0; r < RCH; ++r) o1[r] = ob[(size_t)r * HW];

  __syncthreads();   // barrier 2: half0 reads done (WAR before overwrite)

  // ---------------- HALF 1: build t[288,544) then chunks g=9..16 ----------
  build_dispatch<1>(wv, o1, rowp);
  __syncthreads();   // barrier 3: upS half1 ready
  // abuf slots hold chunk 9 (slot 0) and 10 (slot 1).

#pragma unroll
  for (int ni = 0; ni < 4; ++ni)
    bbuf[0][ni] = *(const f16x8*)&upS[(ni * 16 + ml) * UPROW + q * 8];

#pragma unroll
  for (int cc = 0; cc < 8; ++cc) {
    const int cur = cc % 3;          // global chunk g=9+cc, (9+cc)%3 == cc%3
    if (cc < 6) {
      const int pf = (2 + cc) % 3;   // chunk 11+cc, valid while 11+cc <= 16
      abuf[pf][0] = *(const f16x8*)&wf0[(size_t)(11 + cc) * 512];
      abuf[pf][1] = *(const f16x8*)&wf1[(size_t)(11 + cc) * 512];
    }
    const int cb = cc & 1, nb = cb ^ 1;
    if (cc < 7) {
      const int t0n = (cc + 1) * 32;
#pragma unroll
      for (int ni = 0; ni < 4; ++ni)
        bbuf[nb][ni] = *(const f16x8*)&upS[(ni * 16 + ml) * UPROW + t0n + q * 8];
    }
#pragma unroll
    for (int ni = 0; ni < 4; ++ni) {
      acc[0][ni] = __builtin_amdgcn_mfma_f32_16x16x32_f16(abuf[cur][0], bbuf[cb][ni], acc[0][ni], 0, 0, 0);
      acc[1][ni] = __builtin_amdgcn_mfma_f32_16x16x32_f16(abuf[cur][1], bbuf[cb][ni], acc[1][ni], 0, 0, 0);
    }
    if (cc < 6)
      __builtin_amdgcn_sched_group_barrier(0x020, 2, 0);   // A prefetch
    if (cc < 7)
      __builtin_amdgcn_sched_group_barrier(0x100, 4, 0);   // B ds_reads
    __builtin_amdgcn_sched_group_barrier(0x008, 8, 0);     // MFMAs
  }

  // ---------------- Epilogue: signed sqrt, dword stores -------------------
#pragma unroll
  for (int mi = 0; mi < 2; ++mi) {
#pragma unroll
    for (int reg = 0; reg < 4; ++reg) {
      const int o = wv * 32 + mi * 16 + q * 4 + reg;
      float* yrow = y + ((size_t)(b * COUT + o)) * HW + p0 + ml;
#pragma unroll
      for (int ni = 0; ni < 4; ++ni) {
        float v = acc[mi][ni][reg];
        float s = sqrtf(fabsf(v) + 1e-6f);
        yrow[ni * 16] = v > 0.0f ? s : (v < 0.0f ? -s : 0.0f);
      }
    }
  }
}

// ---------------- Fallback fused kernel (v4, proven) if ws too small -------
__global__ __launch_bounds__(512, 4) void fused_kernel(
    const float* __restrict__ x, const _Float16* __restrict__ w16,
    const _Float16* __restrict__ wr16h, const _Float16* __restrict__ wr16l,
    float* __restrict__ y) {
  __shared__ float outS[RCH * 68];
  __shared__ __align__(16) _Float16 upS[64 * UPROW];

  const int tid  = threadIdx.x;
  const int bx   = blockIdx.x;
  const int b    = bx / 144;
  const int p0   = (bx - b * 144) * 64;
  const int wv   = tid >> 6;
  const int lane = tid & 63;
  const int ml   = lane & 15;
  const int q    = lane >> 4;
  const int mt   = wv >> 2;
  const int nt   = wv & 3;

  {
    f32x4 g1acc;
#pragma unroll
    for (int r2 = 0; r2 < 4; ++r2) g1acc[r2] = 0.0f;

    const int abase = (mt * 16 + ml) * CIN + q * 8;
    f16x8 pa[3][2];
    pa[0][0] = *(const f16x8*)&wr16h[abase + 0 * 32];
    pa[0][1] = *(const f16x8*)&wr16l[abase + 0 * 32];
    pa[1][0] = *(const f16x8*)&wr16h[abase + 1 * 32];
    pa[1][1] = *(const f16x8*)&wr16l[abase + 1 * 32];

    const float* xb = x + (size_t)b * CIN * HW + p0 + nt * 16 + ml;
    float xv[64];
#pragma unroll
    for (int ch = 0; ch < 8; ++ch)
#pragma unroll
      for (int s = 0; s < 8; ++s)
        xv[ch * 8 + s] = xb[(size_t)(ch * 32 + q * 8 + s) * HW];
    __builtin_amdgcn_sched_barrier(0);

#pragma unroll
    for (int ch = 0; ch < 8; ++ch) {
      const int cur = ch % 3;
      if (ch + 2 < 8) {
        const int pf = (ch + 2) % 3;
        pa[pf][0] = *(const f16x8*)&wr16h[abase + (ch + 2) * 32];
        pa[pf][1] = *(const f16x8*)&wr16l[abase + (ch + 2) * 32];
      }
      f16x8 bh, bl;
#pragma unroll
      for (int s = 0; s < 8; ++s) {
        float f = xv[ch * 8 + s];
        _Float16 h = (_Float16)f;
        bh[s] = h;
        bl[s] = (_Float16)(f - (float)h);
      }
      g1acc = __builtin_amdgcn_mfma_f32_16x16x32_f16(pa[cur][0], bh, g1acc, 0, 0, 0);
      g1acc = __builtin_amdgcn_mfma_f32_16x16x32_f16(pa[cur][1], bh, g1acc, 0, 0, 0);
      g1acc = __builtin_amdgcn_mfma_f32_16x16x32_f16(pa[cur][0], bl, g1acc, 0, 0, 0);
    }
#pragma unroll
    for (int reg = 0; reg < 4; ++reg)
      outS[(mt * 16 + q * 4 + reg) * 68 + nt * 16 + ml] = g1acc[reg];
  }

  const _Float16* wf0 = w16 + ((size_t)(wv * 2 + 0) * 17 * 64 + lane) * 8;
  const _Float16* wf1 = w16 + ((size_t)(wv * 2 + 1) * 17 * 64 + lane) * 8;

  f16x8 abuf[3][2];
  abuf[0][0] = *(const f16x8*)&wf0[0];
  abuf[0][1] = *(const f16x8*)&wf1[0];
  abuf[1][0] = *(const f16x8*)&wf0[512];
  abuf[1][1] = *(const f16x8*)&wf1[512];

  __syncthreads();

  f32x4 acc[2][4];
#pragma unroll
  for (int mi = 0; mi < 2; ++mi)
#pragma unroll
    for (int ni = 0; ni < 4; ++ni)
#pragma unroll
      for (int r2 = 0; r2 < 4; ++r2) acc[mi][ni][r2] = 0.0f;

  _Float16* rowp = &upS[lane * UPROW];

  {
    float o[RCH];
#pragma unroll
    for (int r = 0; r < RCH; ++r) o[r] = outS[r * 68 + lane];
    build_dispatch<0>(wv, o, rowp);
  }
  __syncthreads();

  f16x8 bbuf[2][4];
#pragma unroll
  for (int ni = 0; ni < 4; ++ni)
    bbuf[0][ni] = *(const f16x8*)&upS[(ni * 16 + ml) * UPROW + q * 8];

#pragma unroll
  for (int c = 0; c < 9; ++c) {
    const int cur = c % 3;
    const int pf  = (c + 2) % 3;
    abuf[pf][0] = *(const f16x8*)&wf0[(size_t)(c + 2) * 512];
    abuf[pf][1] = *(const f16x8*)&wf1[(size_t)(c + 2) * 512];
    const int cb = c & 1, nb = cb ^ 1;
    if (c < 8) {
      const int t0n = (c + 1) * 32;
#pragma unroll
      for (int ni = 0; ni < 4; ++ni)
        bbuf[nb][ni] = *(const f16x8*)&upS[(ni * 16 + ml) * UPROW + t0n + q * 8];
    }
#pragma unroll
    for (int ni = 0; ni < 4; ++ni) {
      acc[0][ni] = __builtin_amdgcn_mfma_f32_16x16x32_f16(abuf[cur][0], bbuf[cb][ni], acc[0][ni], 0, 0, 0);
      acc[1][ni] = __builtin_amdgcn_mfma_f32_16x16x32_f16(abuf[cur][1], bbuf[cb][ni], acc[1][ni], 0, 0, 0);
    }
  }
  __syncthreads();

  {
    float o[RCH];
#pragma unroll
    for (int r = 0; r < RCH; ++r) o[r] = outS[r * 68 + lane];
    build_dispatch<1>(wv, o, rowp);
  }
  __syncthreads();

#pragma unroll
  for (int ni = 0; ni < 4; ++ni)
    bbuf[0][ni] = *(const f16x8*)&upS[(ni * 16 + ml) * UPROW + q * 8];

#pragma unroll
  for (int cc = 0; cc < 8; ++cc) {
    const int cur = cc % 3;
    if (cc < 6) {
      const int pf = (2 + cc) % 3;
      abuf[pf][0] = *(const f16x8*)&wf0[(size_t)(11 + cc) * 512];
      abuf[pf][1] = *(const f16x8*)&wf1[(size_t)(11 + cc) * 512];
    }
    const int cb = cc & 1, nb = cb ^ 1;
    if (cc < 7) {
      const int t0n = (cc + 1) * 32;
#pragma unroll
      for (int ni = 0; ni < 4; ++ni)
        bbuf[nb][ni] = *(const f16x8*)&upS[(ni * 16 + ml) * UPROW + t0n + q * 8];
    }
#pragma unroll
    for (int ni = 0; ni < 4; ++ni) {
      acc[0][ni] = __builtin_amdgcn_mfma_f32_16x16x32_f16(abuf[cur][0], bbuf[cb][ni], acc[0][ni], 0, 0, 0);
      acc[1][ni] = __builtin_amdgcn_mfma_f32_16x16x32_f16(abuf[cur][1], bbuf[cb][ni], acc[1][ni], 0, 0, 0);
    }
  }

#pragma unroll
  for (int mi = 0; mi < 2; ++mi) {
#pragma unroll
    for (int reg = 0; reg < 4; ++reg) {
      const int o = wv * 32 + mi * 16 + q * 4 + reg;
      float* yrow = y + ((size_t)(b * COUT + o)) * HW + p0 + ml;
#pragma unroll
      for (int ni = 0; ni < 4; ++ni) {
        float v = acc[mi][ni][reg];
        float s = sqrtf(fabsf(v) + 1e-6f);
        yrow[ni * 16] = v > 0.0f ? s : (v < 0.0f ? -s : 0.0f);
      }
    }
  }
}

extern "C" void kernel_launch(void* const* d_in, const int* in_sizes, int n_in,
                              void* d_out, int out_size, void* d_ws, size_t ws_size,
                              hipStream_t stream) {
  const float* x         = (const float*)d_in[0];
  const float* w_reduce  = (const float*)d_in[1];
  const float* w_recover = (const float*)d_in[2];
  float* y = (float*)d_out;

  _Float16* w16   = (_Float16*)d_ws;                            // 278528 B
  _Float16* wr16h = (_Float16*)((char*)d_ws + 278528);          // 16384 B
  _Float16* wr16l = (_Float16*)((char*)d_ws + 278528 + 16384);  // 16384 B
  float*    wT    = (float*)((char*)d_ws + 311296);             // 32768 B
  float*    outp  = (float*)((char*)d_ws + 344064);             // 9437184 B
  const size_t NEED = 344064 + (size_t)NB * RCH * HW * 4;

  convert_kernel<<<WFROWS + 17, 256, 0, stream>>>(w_reduce, w_recover, w16,
                                                  wr16h, wr16l, wT);
  if (ws_size >= NEED) {
    reduce_kernel<<<NB * (HW / 128), 256, 0, stream>>>(x, wr16h, wr16l, outp);
    gemm2_kernel<<<NB * (HW / 64), 512, 0, stream>>>(outp, w16, y);
  } else {
    fused_kernel<<<NB * (HW / 64), 512, 0, stream>>>(x, w16, wr16h, wr16l, y);
  }
}

// Round 9
// 164.814 us; speedup vs baseline: 1.5748x; 1.0203x over previous
//
#include <hip/hip_runtime.h>
#include <hip/hip_bf16.h>
#include <math.h>

// BilinearGate. B=8, Cin=256, HW=9216, R=32, TRI=528, Cout=256.
// v10: re-fused single kernel = v4 structure with phase-1 REPLACED by v9's
// LDS-staged-x MFMA GEMM1 (the strided x loads were v0-v4's poison; the
// split proved the staged form is ~25% faster and the intermediate
// round-trip (9.4MB write + read + o-load chain) is pure tax).
// Phase 1: per 32-ch chunk, x HBM->LDS coalesced (512thr x f32x4 = 8KB),
//   dbuf + 1 barrier/chunk; wave wv owns (mt=wv>>2, nt=wv&3) 16x16 tile
//   (v2-proven); B-frag = per-lane b32 xS reads == v0's xv semantics;
//   A-frag/outS-write = v0-proven lines. xS stride 70 -> 2-way reads (free).
// Phase 2: verbatim v6 gemm2 body (o from outS, build, 17 chunks, SGB pins,
//   UPROW=300, depth-2 w16 pipeline, 3 barriers).
// LDS 17.9+8.7+38.4 = 65KB -> 2 blocks/CU. 12 barriers total.
#define HW     9216
#define CIN    256
#define RCH    32
#define NTRI   528
#define COUT   256
#define NB     8
#define WFROWS 272   // 8 wv * 2 mi * 17 c fragment-rows of 512 halfs
#define UPROW  300   // halfs per upS row (288 data + 12 pad) = 600 B
#define XROW   70    // xS row stride in dwords (64 + 6 pad; 280B, 8B-mult)

typedef _Float16 f16x8 __attribute__((ext_vector_type(8)));
typedef _Float16 f16x4 __attribute__((ext_vector_type(4)));
typedef float    f32x4 __attribute__((ext_vector_type(4)));
typedef float    f32x2 __attribute__((ext_vector_type(2)));

struct TriTab { unsigned char i[544]; unsigned char j[544]; };
constexpr TriTab make_tri() {
  TriTab t{};
  int ii = 0, jj = 0;
  for (int k = 0; k < 544; ++k) {
    if (k < NTRI) {
      t.i[k] = (unsigned char)ii; t.j[k] = (unsigned char)jj;
      if (++jj == 32) { ++ii; jj = ii; }
    } else { t.i[k] = 0; t.j[k] = 0; }
  }
  return t;
}
constexpr TriTab TRI = make_tri();

// Wave TQ (0..7) builds its share of up[p][t] for one half.
// HALF 0: t in [TQ*36, TQ*36+36). HALF 1: t in [288+TQ*32, 288+TQ*32+32).
template<int TQ, int HALF>
__device__ __forceinline__ void build_up(const float (&o)[RCH], _Float16* rowp) {
  constexpr int NG  = HALF ? 8 : 9;
  constexpr int TLB = TQ * (HALF ? 32 : 36);
  constexpr int TB  = HALF ? 288 : 0;
#pragma unroll
  for (int g = 0; g < NG; ++g) {
    f16x4 v;
#pragma unroll
    for (int s = 0; s < 4; ++s) {
      const int tl = TLB + g * 4 + s;
      const int t  = TB + tl;
      float f = (t < NTRI) ? o[TRI.i[t]] * o[TRI.j[t]] : 0.0f;
      v[s] = (_Float16)f;
    }
    *(f16x4*)&rowp[TLB + g * 4] = v;
  }
}

template<int HALF>
__device__ __forceinline__ void build_dispatch(int wv, const float (&o)[RCH],
                                               _Float16* rowp) {
  switch (wv) {
    case 0: build_up<0, HALF>(o, rowp); break;
    case 1: build_up<1, HALF>(o, rowp); break;
    case 2: build_up<2, HALF>(o, rowp); break;
    case 3: build_up<3, HALF>(o, rowp); break;
    case 4: build_up<4, HALF>(o, rowp); break;
    case 5: build_up<5, HALF>(o, rowp); break;
    case 6: build_up<6, HALF>(o, rowp); break;
    default: build_up<7, HALF>(o, rowp); break;
  }
}

// w16 fragment layout: element (((wv*2+mi)*17 + c)*64 + lane)*8 + s holds
// w_recover[o][t] with o = wv*32+mi*16+(lane&15), t = c*32+(lane>>4)*8+s.
__global__ __launch_bounds__(256) void convert_kernel(
    const float* __restrict__ w_reduce, const float* __restrict__ w_recover,
    _Float16* __restrict__ w16, _Float16* __restrict__ wr16h,
    _Float16* __restrict__ wr16l) {
  const int bx = blockIdx.x;
  const int tid = threadIdx.x;
  if (bx < WFROWS) {
    const int wv  = bx / 34;
    const int rem = bx - wv * 34;
    const int mi  = rem / 17;
    const int c   = rem - mi * 17;
    const int lane = tid >> 2;           // 0..63
    const int s0   = (tid & 3) * 2;      // 0,2,4,6
    const int o = wv * 32 + mi * 16 + (lane & 15);
    const int t = c * 32 + (lane >> 4) * 8 + s0;
    float f0 = (t     < NTRI) ? w_recover[(size_t)o * NTRI + t]     : 0.0f;
    float f1 = (t + 1 < NTRI) ? w_recover[(size_t)o * NTRI + t + 1] : 0.0f;
    _Float16* p = &w16[((size_t)bx * 64 + lane) * 8 + s0];
    p[0] = (_Float16)f0;
    p[1] = (_Float16)f1;
  } else {
    int e = (bx - WFROWS) * 512 + tid;
#pragma unroll
    for (int k = 0; k < 2; ++k, e += 256) {
      float f = w_reduce[e];
      _Float16 h = (_Float16)f;
      wr16h[e] = h;
      wr16l[e] = (_Float16)(f - (float)h);
    }
  }
}

// ---------------- Fused kernel: staged-x GEMM1 + up-build + GEMM2 -----------
__global__ __launch_bounds__(512, 4) void fused_kernel(
    const float* __restrict__ x, const _Float16* __restrict__ w16,
    const _Float16* __restrict__ wr16h, const _Float16* __restrict__ wr16l,
    float* __restrict__ y) {
  __shared__ __align__(16) float xS[2][RCH][XROW];     // 17.9 KB
  __shared__ float outS[RCH * 68];                     // 8.7 KB
  __shared__ __align__(16) _Float16 upS[64 * UPROW];   // 38.4 KB

  const int tid  = threadIdx.x;
  const int bx   = blockIdx.x;          // 1152 = 8 b * 144 px-tiles
  const int b    = bx / 144;
  const int p0   = (bx - b * 144) * 64;
  const int wv   = tid >> 6;
  const int lane = tid & 63;
  const int ml   = lane & 15;
  const int q    = lane >> 4;
  const int mt   = wv >> 2;             // phase-1 out-row half (0..1)
  const int nt   = wv & 3;              // phase-1 px quarter (0..3)
  const int ci   = tid >> 4;            // staging c-row (0..31)
  const int pxi  = (tid & 15) * 4;      // staging px base (0..60)

  // ---------------- Phase 1: GEMM1 with LDS-staged x ----------------------
  {
    const float* xg = x + (size_t)b * CIN * HW + p0 + pxi;
    const int arow = (mt * 16 + ml) * CIN + q * 8;

    f32x4 g1acc;
#pragma unroll
    for (int r2 = 0; r2 < 4; ++r2) g1acc[r2] = 0.0f;

    // prologue: stage chunk 0, A-frags chunk 0
    f32x4 gx = *(const f32x4*)&xg[(size_t)ci * HW];
    f16x8 af[2][2];                     // [parity][h/l]
    af[0][0] = *(const f16x8*)&wr16h[arow];
    af[0][1] = *(const f16x8*)&wr16l[arow];
    *(f32x2*)&xS[0][ci][pxi]     = f32x2{gx[0], gx[1]};
    *(f32x2*)&xS[0][ci][pxi + 2] = f32x2{gx[2], gx[3]};
    __syncthreads();

#pragma unroll
    for (int ch = 0; ch < 8; ++ch) {
      const int cur = ch & 1, nxt = cur ^ 1;
      if (ch < 7) {
        const int c0n = (ch + 1) * 32;
        gx = *(const f32x4*)&xg[(size_t)(c0n + ci) * HW];
        af[nxt][0] = *(const f16x8*)&wr16h[arow + c0n];
        af[nxt][1] = *(const f16x8*)&wr16l[arow + c0n];
      }
      // B-frag == v0 semantics: x[(c0+q*8+s)*HW + p0 + nt*16 + ml]
      float bf[8];
#pragma unroll
      for (int s = 0; s < 8; ++s) bf[s] = xS[cur][q * 8 + s][nt * 16 + ml];
      f16x8 bh, bl;
#pragma unroll
      for (int s = 0; s < 8; ++s) {
        _Float16 h = (_Float16)bf[s];
        bh[s] = h;
        bl[s] = (_Float16)(bf[s] - (float)h);
      }
      g1acc = __builtin_amdgcn_mfma_f32_16x16x32_f16(af[cur][0], bh, g1acc, 0, 0, 0);
      g1acc = __builtin_amdgcn_mfma_f32_16x16x32_f16(af[cur][1], bh, g1acc, 0, 0, 0);
      g1acc = __builtin_amdgcn_mfma_f32_16x16x32_f16(af[cur][0], bl, g1acc, 0, 0, 0);
      if (ch < 7) {
        *(f32x2*)&xS[nxt][ci][pxi]     = f32x2{gx[0], gx[1]};
        *(f32x2*)&xS[nxt][ci][pxi + 2] = f32x2{gx[2], gx[3]};
        __builtin_amdgcn_sched_group_barrier(0x020, 3, 0);   // gx + 2 af
        __builtin_amdgcn_sched_group_barrier(0x100, 8, 0);   // B ds_reads
        __builtin_amdgcn_sched_group_barrier(0x002, 28, 0);  // cvt VALU
        __builtin_amdgcn_sched_group_barrier(0x008, 3, 0);   // MFMAs
        __builtin_amdgcn_sched_group_barrier(0x200, 2, 0);   // ds_writes
        __syncthreads();
      }
    }
    // D[row=q*4+reg][col=ml]: r = mt*16+q*4+reg, p = nt*16+ml (v0-proven)
#pragma unroll
    for (int reg = 0; reg < 4; ++reg)
      outS[(mt * 16 + q * 4 + reg) * 68 + nt * 16 + ml] = g1acc[reg];
  }

  // Fragment bases into pre-swizzled w16 (chunk c at +c*512 halfs).
  const _Float16* wf0 = w16 + ((size_t)(wv * 2 + 0) * 17 * 64 + lane) * 8;
  const _Float16* wf1 = w16 + ((size_t)(wv * 2 + 1) * 17 * 64 + lane) * 8;

  // A-stream depth-2 prologue: chunks 0,1 in flight across the barrier.
  f16x8 abuf[3][2];
  abuf[0][0] = *(const f16x8*)&wf0[0];
  abuf[0][1] = *(const f16x8*)&wf1[0];
  abuf[1][0] = *(const f16x8*)&wf0[512];
  abuf[1][1] = *(const f16x8*)&wf1[512];

  __syncthreads();   // outS complete

  f32x4 acc[2][4];
#pragma unroll
  for (int mi = 0; mi < 2; ++mi)
#pragma unroll
    for (int ni = 0; ni < 4; ++ni)
#pragma unroll
      for (int r2 = 0; r2 < 4; ++r2) acc[mi][ni][r2] = 0.0f;

  _Float16* rowp = &upS[lane * UPROW];

  // ---------------- HALF 0: build t[0,288) then chunks c=0..8 -------------
  {
    float o[RCH];
#pragma unroll
    for (int r = 0; r < RCH; ++r) o[r] = outS[r * 68 + lane];
    build_dispatch<0>(wv, o, rowp);
  }
  __syncthreads();   // upS half0 ready

  f16x8 bbuf[2][4];
#pragma unroll
  for (int ni = 0; ni < 4; ++ni)
    bbuf[0][ni] = *(const f16x8*)&upS[(ni * 16 + ml) * UPROW + q * 8];

#pragma unroll
  for (int c = 0; c < 9; ++c) {
    const int cur = c % 3;
    const int pf  = (c + 2) % 3;     // chunks c+2 <= 10 < 17: always valid
    abuf[pf][0] = *(const f16x8*)&wf0[(size_t)(c + 2) * 512];
    abuf[pf][1] = *(const f16x8*)&wf1[(size_t)(c + 2) * 512];
    const int cb = c & 1, nb = cb ^ 1;
    if (c < 8) {
      const int t0n = (c + 1) * 32;
#pragma unroll
      for (int ni = 0; ni < 4; ++ni)
        bbuf[nb][ni] = *(const f16x8*)&upS[(ni * 16 + ml) * UPROW + t0n + q * 8];
    }
#pragma unroll
    for (int ni = 0; ni < 4; ++ni) {
      acc[0][ni] = __builtin_amdgcn_mfma_f32_16x16x32_f16(abuf[cur][0], bbuf[cb][ni], acc[0][ni], 0, 0, 0);
      acc[1][ni] = __builtin_amdgcn_mfma_f32_16x16x32_f16(abuf[cur][1], bbuf[cb][ni], acc[1][ni], 0, 0, 0);
    }
    __builtin_amdgcn_sched_group_barrier(0x020, 2, 0);     // A prefetch
    if (c < 8)
      __builtin_amdgcn_sched_group_barrier(0x100, 4, 0);   // B ds_reads
    __builtin_amdgcn_sched_group_barrier(0x008, 8, 0);     // MFMAs
  }
  __syncthreads();   // half0 reads done (WAR before overwrite)

  // ---------------- HALF 1: build t[288,544) then chunks g=9..16 ----------
  {
    float o[RCH];
#pragma unroll
    for (int r = 0; r < RCH; ++r) o[r] = outS[r * 68 + lane];
    build_dispatch<1>(wv, o, rowp);
  }
  __syncthreads();   // upS half1 ready
  // abuf slots hold chunk 9 (slot 0) and 10 (slot 1).

#pragma unroll
  for (int ni = 0; ni < 4; ++ni)
    bbuf[0][ni] = *(const f16x8*)&upS[(ni * 16 + ml) * UPROW + q * 8];

#pragma unroll
  for (int cc = 0; cc < 8; ++cc) {
    const int cur = cc % 3;          // global chunk g=9+cc, (9+cc)%3 == cc%3
    if (cc < 6) {
      const int pf = (2 + cc) % 3;   // chunk 11+cc, valid while 11+cc <= 16
      abuf[pf][0] = *(const f16x8*)&wf0[(size_t)(11 + cc) * 512];
      abuf[pf][1] = *(const f16x8*)&wf1[(size_t)(11 + cc) * 512];
    }
    const int cb = cc & 1, nb = cb ^ 1;
    if (cc < 7) {
      const int t0n = (cc + 1) * 32;
#pragma unroll
      for (int ni = 0; ni < 4; ++ni)
        bbuf[nb][ni] = *(const f16x8*)&upS[(ni * 16 + ml) * UPROW + t0n + q * 8];
    }
#pragma unroll
    for (int ni = 0; ni < 4; ++ni) {
      acc[0][ni] = __builtin_amdgcn_mfma_f32_16x16x32_f16(abuf[cur][0], bbuf[cb][ni], acc[0][ni], 0, 0, 0);
      acc[1][ni] = __builtin_amdgcn_mfma_f32_16x16x32_f16(abuf[cur][1], bbuf[cb][ni], acc[1][ni], 0, 0, 0);
    }
    if (cc < 6)
      __builtin_amdgcn_sched_group_barrier(0x020, 2, 0);   // A prefetch
    if (cc < 7)
      __builtin_amdgcn_sched_group_barrier(0x100, 4, 0);   // B ds_reads
    __builtin_amdgcn_sched_group_barrier(0x008, 8, 0);     // MFMAs
  }

  // ---------------- Epilogue: signed sqrt, dword stores -------------------
#pragma unroll
  for (int mi = 0; mi < 2; ++mi) {
#pragma unroll
    for (int reg = 0; reg < 4; ++reg) {
      const int o = wv * 32 + mi * 16 + q * 4 + reg;
      float* yrow = y + ((size_t)(b * COUT + o)) * HW + p0 + ml;
#pragma unroll
      for (int ni = 0; ni < 4; ++ni) {
        float v = acc[mi][ni][reg];
        float s = sqrtf(fabsf(v) + 1e-6f);
        yrow[ni * 16] = v > 0.0f ? s : (v < 0.0f ? -s : 0.0f);
      }
    }
  }
}

extern "C" void kernel_launch(void* const* d_in, const int* in_sizes, int n_in,
                              void* d_out, int out_size, void* d_ws, size_t ws_size,
                              hipStream_t stream) {
  const float* x         = (const float*)d_in[0];
  const float* w_reduce  = (const float*)d_in[1];
  const float* w_recover = (const float*)d_in[2];
  float* y = (float*)d_out;

  _Float16* w16   = (_Float16*)d_ws;                            // 278528 B
  _Float16* wr16h = (_Float16*)((char*)d_ws + 278528);          // 16384 B
  _Float16* wr16l = (_Float16*)((char*)d_ws + 278528 + 16384);  // 16384 B

  convert_kernel<<<WFROWS + 16, 256, 0, stream>>>(w_reduce, w_recover, w16,
                                                  wr16h, wr16l);
  fused_kernel<<<NB * (HW / 64), 512, 0, stream>>>(x, w16, wr16h, wr16l, y);
}